// Round 3
// baseline (86.046 us; speedup 1.0000x reference)
//
#include <hip/hip_runtime.h>
#include <math.h>

constexpr int S_ = 4096;
constexpr int B_ = 64;
constexpr int H_ = 256;

// ws float layout:
// 0     : dW [B*H] = 16384
// 16384 : pc [B]
// 16448 : scores [B*S] = 262144

__global__ __launch_bounds__(256) void k1_prep(const float* __restrict__ d,
                                               const float* __restrict__ W_a,
                                               const float* __restrict__ W_p,
                                               const float* __restrict__ v_p,
                                               float* __restrict__ dW,
                                               float* __restrict__ pc) {
  int b = blockIdx.x;
  int h = threadIdx.x;
  float acc_a = 0.f, acc_p = 0.f;
  const float* db = d + b * H_;
  for (int k = 0; k < H_; ++k) {
    float dv = db[k];
    acc_a = fmaf(dv, W_a[k * H_ + h], acc_a);
    acc_p = fmaf(dv, W_p[k * H_ + h], acc_p);
  }
  dW[b * H_ + h] = acc_a;
  float prod = tanhf(acc_p) * v_p[h];
  __shared__ float red[256];
  red[h] = prod;
  __syncthreads();
  for (int st = 128; st > 0; st >>= 1) {
    if (h < st) red[h] += red[h + st];
    __syncthreads();
  }
  if (h == 0) {
    pc[b] = (float)S_ / (1.f + expf(-red[0]));   // sigmoid * S
  }
}

// scores kernel, v3: block = 4 consecutive s (256KB sequential DRAM span).
// lane -> (b_local = lane>>2, sub = lane&3); wave w covers b in [16w,16w+16).
// Each load instr: 4 consecutive lanes read 4 consecutive float4 of one e-row
// -> 16 complete 64B lines per instr, zero over-fetch. Reduce = 2 quad shfl.
__global__ __launch_bounds__(256) void k2_scores(const float* __restrict__ e,
                                                 const float* __restrict__ dW,
                                                 float* __restrict__ scores) {
  int t = threadIdx.x;
  int wave = t >> 6;
  int lane = t & 63;
  int bl = lane >> 2;            // 0..15
  int sub = lane & 3;            // 0..3
  int b = wave * 16 + bl;        // global b
  int s0 = blockIdx.x * 4;

  // stage this thread's dW chunks (c = sub + 4j) in registers, reused 4 rows
  const float4* dW4 = (const float4*)(dW + b * H_);
  float4 wreg[16];
#pragma unroll
  for (int j = 0; j < 16; ++j) wreg[j] = dW4[sub + 4 * j];

  float sc[4];
#pragma unroll
  for (int r = 0; r < 4; ++r) {
    const float4* erow = (const float4*)(e + ((size_t)(s0 + r) * B_ + b) * H_);
    float acc = 0.f;
#pragma unroll
    for (int half = 0; half < 2; ++half) {
      float4 ev[8];
#pragma unroll
      for (int j = 0; j < 8; ++j) ev[j] = erow[sub + 4 * (half * 8 + j)];
#pragma unroll
      for (int j = 0; j < 8; ++j) {
        const float4 wv = wreg[half * 8 + j];
        acc = fmaf(ev[j].x, wv.x, fmaf(ev[j].y, wv.y,
              fmaf(ev[j].z, wv.z, fmaf(ev[j].w, wv.w, acc))));
      }
    }
    acc += __shfl_xor(acc, 1, 64);
    acc += __shfl_xor(acc, 2, 64);
    sc[r] = acc;
  }

  __shared__ float tile[4][64];
  if (sub == 0) {
#pragma unroll
    for (int r = 0; r < 4; ++r) tile[r][b] = sc[r];
  }
  __syncthreads();
  int b_out = t >> 2, r = t & 3;
  scores[b_out * S_ + s0 + r] = tile[r][b_out];
}

// fused: per-b softmax stats + w write (transposed) + window context + linear + ReLU
__global__ __launch_bounds__(256) void kF(const float* __restrict__ scores,
                                          const float* __restrict__ pc,
                                          const float* __restrict__ e,
                                          const float* __restrict__ d,
                                          const float* __restrict__ lin_w,
                                          const float* __restrict__ lin_b,
                                          float* __restrict__ out,
                                          float* __restrict__ w_out) {
  int b = blockIdx.x;
  int t = threadIdx.x;
  const float* sc = scores + b * S_;
  float v[16];
  float lm = -INFINITY;
#pragma unroll
  for (int k = 0; k < 16; ++k) {
    v[k] = sc[t + k * 256];
    lm = fmaxf(lm, v[k]);
  }
  __shared__ float red[256];
  red[t] = lm;
  __syncthreads();
  for (int st = 128; st > 0; st >>= 1) {
    if (t < st) red[t] = fmaxf(red[t], red[t + st]);
    __syncthreads();
  }
  float mb = red[0];
  __syncthreads();
  float ls = 0.f;
#pragma unroll
  for (int k = 0; k < 16; ++k) ls += expf(v[k] - mb);
  red[t] = ls;
  __syncthreads();
  for (int st = 128; st > 0; st >>= 1) {
    if (t < st) red[t] += red[t + st];
    __syncthreads();
  }
  float inv_l = 1.f / red[0];
  float pcb = pc[b];
#pragma unroll
  for (int k = 0; k < 16; ++k) {
    int s = t + k * 256;
    float diff = pcb - (float)s;
    float p = (fabsf(diff) <= 2.f) ? expf(-0.5f * diff * diff) : 0.f;
    w_out[(size_t)s * B_ + b] = expf(v[k] - mb) * inv_l * p;
  }
  int s0 = max(0, (int)ceilf(pcb - 2.f));
  int s1 = min(S_ - 1, (int)floorf(pcb + 2.f));
  float ctx = 0.f;
  for (int s = s0; s <= s1; ++s) {
    float diff = pcb - (float)s;
    float wv = expf(sc[s] - mb) * inv_l * expf(-0.5f * diff * diff);
    ctx = fmaf(wv, e[((size_t)s * B_ + b) * H_ + t], ctx);
  }
  __shared__ float x[512];
  x[t] = ctx;
  x[256 + t] = d[b * H_ + t];
  __syncthreads();
  float acc = lin_b[t];
  const float4* lw = (const float4*)(lin_w + t * 2 * H_);
  const float4* xv = (const float4*)x;
#pragma unroll 4
  for (int k = 0; k < 128; ++k) {
    float4 a4 = lw[k];
    float4 b4 = xv[k];
    acc += a4.x * b4.x + a4.y * b4.y + a4.z * b4.z + a4.w * b4.w;
  }
  out[b * H_ + t] = fmaxf(acc, 0.f);
}

extern "C" void kernel_launch(void* const* d_in, const int* in_sizes, int n_in,
                              void* d_out, int out_size, void* d_ws, size_t ws_size,
                              hipStream_t stream) {
  const float* e     = (const float*)d_in[0];
  const float* d     = (const float*)d_in[1];
  const float* W_a   = (const float*)d_in[2];
  const float* W_p   = (const float*)d_in[3];
  const float* v_p   = (const float*)d_in[4];
  const float* lin_w = (const float*)d_in[5];
  const float* lin_b = (const float*)d_in[6];

  float* out   = (float*)d_out;        // [1,B,H] = 16384 floats
  float* w_out = out + B_ * H_;        // [S,B]   = 262144 floats

  float* ws     = (float*)d_ws;
  float* dW     = ws;
  float* pc     = ws + 16384;
  float* scores = ws + 16448;

  k1_prep<<<B_, 256, 0, stream>>>(d, W_a, W_p, v_p, dW, pc);
  k2_scores<<<S_ / 4, 256, 0, stream>>>(e, dW, scores);
  kF<<<B_, 256, 0, stream>>>(scores, pc, e, d, lin_w, lin_b, out, w_out);
}

// Round 4
// 80.064 us; speedup vs baseline: 1.0747x; 1.0747x over previous
//
#include <hip/hip_runtime.h>
#include <math.h>

constexpr int S_ = 4096;
constexpr int B_ = 64;
constexpr int H_ = 256;

// ws float layout:
// 0     : dW [B*H] = 16384
// 16384 : pc [B]
// 16448 : scores [B*S] = 262144

// k1 v2: 64 blocks x 1024 threads; thread=(h=t&255, kc=t>>8) splits the
// k-reduction 4x (64 iters/thread instead of 256) -> 4x less load latency.
__global__ __launch_bounds__(1024) void k1_prep(const float* __restrict__ d,
                                                const float* __restrict__ W_a,
                                                const float* __restrict__ W_p,
                                                const float* __restrict__ v_p,
                                                float* __restrict__ dW,
                                                float* __restrict__ pc) {
  int b = blockIdx.x;
  int t = threadIdx.x;
  int h = t & 255;
  int kc = t >> 8;
  const float* db = d + b * H_;
  float acc_a = 0.f, acc_p = 0.f;
#pragma unroll 8
  for (int k = kc * 64; k < kc * 64 + 64; ++k) {
    float dv = db[k];
    acc_a = fmaf(dv, W_a[k * H_ + h], acc_a);
    acc_p = fmaf(dv, W_p[k * H_ + h], acc_p);
  }
  __shared__ float part[4][256];
  part[kc][h] = acc_a;
  __syncthreads();
  float dwa = 0.f;
  if (t < 256) dwa = part[0][t] + part[1][t] + part[2][t] + part[3][t];
  __syncthreads();
  part[kc][h] = acc_p;
  __syncthreads();
  __shared__ float red[256];
  if (t < 256) {
    dW[b * H_ + t] = dwa;
    float dwp = part[0][t] + part[1][t] + part[2][t] + part[3][t];
    red[t] = tanhf(dwp) * v_p[t];
  }
  __syncthreads();
  for (int st = 128; st > 0; st >>= 1) {
    if (t < st) red[t] += red[t + st];
    __syncthreads();
  }
  if (t == 0) pc[b] = (float)S_ / (1.f + expf(-red[0]));
}

// scores kernel (unchanged control): block = 4 consecutive s rows.
__global__ __launch_bounds__(256) void k2_scores(const float* __restrict__ e,
                                                 const float* __restrict__ dW,
                                                 float* __restrict__ scores) {
  int t = threadIdx.x;
  int wave = t >> 6;
  int lane = t & 63;
  int bl = lane >> 2;
  int sub = lane & 3;
  int b = wave * 16 + bl;
  int s0 = blockIdx.x * 4;

  const float4* dW4 = (const float4*)(dW + b * H_);
  float4 wreg[16];
#pragma unroll
  for (int j = 0; j < 16; ++j) wreg[j] = dW4[sub + 4 * j];

  float sc[4];
#pragma unroll
  for (int r = 0; r < 4; ++r) {
    const float4* erow = (const float4*)(e + ((size_t)(s0 + r) * B_ + b) * H_);
    float acc = 0.f;
#pragma unroll
    for (int half = 0; half < 2; ++half) {
      float4 ev[8];
#pragma unroll
      for (int j = 0; j < 8; ++j) ev[j] = erow[sub + 4 * (half * 8 + j)];
#pragma unroll
      for (int j = 0; j < 8; ++j) {
        const float4 wv = wreg[half * 8 + j];
        acc = fmaf(ev[j].x, wv.x, fmaf(ev[j].y, wv.y,
              fmaf(ev[j].z, wv.z, fmaf(ev[j].w, wv.w, acc))));
      }
    }
    acc += __shfl_xor(acc, 1, 64);
    acc += __shfl_xor(acc, 2, 64);
    sc[r] = acc;
  }

  __shared__ float tile[4][64];
  if (sub == 0) {
#pragma unroll
    for (int r = 0; r < 4; ++r) tile[r][b] = sc[r];
  }
  __syncthreads();
  int b_out = t >> 2, r = t & 3;
  scores[b_out * S_ + s0 + r] = tile[r][b_out];
}

// kF v2: 64 blocks x 1024 threads. 4 scores/thread for stats & w_out;
// linear split 4-way per output (h=t>>2, part=t&3) with LDS reduce.
__global__ __launch_bounds__(1024) void kF(const float* __restrict__ scores,
                                           const float* __restrict__ pc,
                                           const float* __restrict__ e,
                                           const float* __restrict__ d,
                                           const float* __restrict__ lin_w,
                                           const float* __restrict__ lin_b,
                                           float* __restrict__ out,
                                           float* __restrict__ w_out) {
  int b = blockIdx.x;
  int t = threadIdx.x;
  const float* sc = scores + b * S_;
  float v[4];
  float lm = -INFINITY;
#pragma unroll
  for (int k = 0; k < 4; ++k) {
    v[k] = sc[t + k * 1024];
    lm = fmaxf(lm, v[k]);
  }
  __shared__ float red[1024];
  red[t] = lm;
  __syncthreads();
  for (int st = 512; st > 0; st >>= 1) {
    if (t < st) red[t] = fmaxf(red[t], red[t + st]);
    __syncthreads();
  }
  float mb = red[0];
  __syncthreads();
  float ls = 0.f;
#pragma unroll
  for (int k = 0; k < 4; ++k) ls += expf(v[k] - mb);
  red[t] = ls;
  __syncthreads();
  for (int st = 512; st > 0; st >>= 1) {
    if (t < st) red[t] += red[t + st];
    __syncthreads();
  }
  float inv_l = 1.f / red[0];
  float pcb = pc[b];
#pragma unroll
  for (int k = 0; k < 4; ++k) {
    int s = t + k * 1024;
    float diff = pcb - (float)s;
    float p = (fabsf(diff) <= 2.f) ? expf(-0.5f * diff * diff) : 0.f;
    w_out[(size_t)s * B_ + b] = expf(v[k] - mb) * inv_l * p;
  }
  __shared__ float x[512];
  if (t < 256) {
    int s0 = max(0, (int)ceilf(pcb - 2.f));
    int s1 = min(S_ - 1, (int)floorf(pcb + 2.f));
    float ctx = 0.f;
    for (int s = s0; s <= s1; ++s) {
      float diff = pcb - (float)s;
      float wv = expf(sc[s] - mb) * inv_l * expf(-0.5f * diff * diff);
      ctx = fmaf(wv, e[((size_t)s * B_ + b) * H_ + t], ctx);
    }
    x[t] = ctx;
  } else if (t < 512) {
    x[t] = d[b * H_ + (t - 256)];
  }
  __syncthreads();
  int h = t >> 2, part = t & 3;
  const float4* lw = (const float4*)(lin_w + h * 2 * H_) + part * 32;
  const float4* xv = (const float4*)x + part * 32;
  float acc = 0.f;
#pragma unroll 8
  for (int k = 0; k < 32; ++k) {
    float4 a4 = lw[k];
    float4 b4 = xv[k];
    acc += a4.x * b4.x + a4.y * b4.y + a4.z * b4.z + a4.w * b4.w;
  }
  red[t] = acc;
  __syncthreads();
  if (t < 256) {
    float r = red[4 * t] + red[4 * t + 1] + red[4 * t + 2] + red[4 * t + 3] + lin_b[t];
    out[b * H_ + t] = fmaxf(r, 0.f);
  }
}

extern "C" void kernel_launch(void* const* d_in, const int* in_sizes, int n_in,
                              void* d_out, int out_size, void* d_ws, size_t ws_size,
                              hipStream_t stream) {
  const float* e     = (const float*)d_in[0];
  const float* d     = (const float*)d_in[1];
  const float* W_a   = (const float*)d_in[2];
  const float* W_p   = (const float*)d_in[3];
  const float* v_p   = (const float*)d_in[4];
  const float* lin_w = (const float*)d_in[5];
  const float* lin_b = (const float*)d_in[6];

  float* out   = (float*)d_out;        // [1,B,H] = 16384 floats
  float* w_out = out + B_ * H_;        // [S,B]   = 262144 floats

  float* ws     = (float*)d_ws;
  float* dW     = ws;
  float* pc     = ws + 16384;
  float* scores = ws + 16448;

  k1_prep<<<B_, 1024, 0, stream>>>(d, W_a, W_p, v_p, dW, pc);
  k2_scores<<<S_ / 4, 256, 0, stream>>>(e, dW, scores);
  kF<<<B_, 1024, 0, stream>>>(scores, pc, e, d, lin_w, lin_b, out, w_out);
}